// Round 11
// baseline (107.358 us; speedup 1.0000x reference)
//
#include <hip/hip_runtime.h>
#include <math.h>

// Problem constants (fixed by the reference):
#define B_ 4
#define C_ 192
#define L_ 4096
#define CO_ 64
#define LOG2E 1.44269504088896340736f

using half8 = __attribute__((ext_vector_type(8))) _Float16;
using half4v = __attribute__((ext_vector_type(4))) _Float16;
using half2v = __attribute__((ext_vector_type(2))) _Float16;
using f32x16 = __attribute__((ext_vector_type(16))) float;

#if __has_builtin(__builtin_amdgcn_exp2f)
#define EXP2(x) __builtin_amdgcn_exp2f(x)
#else
#define EXP2(x) exp2f(x)
#endif

__device__ inline half2v pkrtz(float a, float b) {
  return __builtin_bit_cast(half2v, __builtin_amdgcn_cvt_pkrtz(a, b));
}

// ---------------------------------------------------------------------------
// ws layout (halfs unless noted; fully rewritten every call):
//   Wpack : [w][og][ks][lane]x8  4*2*12*64*8 = 49152 (96 KB, frag order)
//   fPack : [b][T][ks][lane]x8   = 2 MB (A-frags of f, xLOG2E)
//   gPack : [b][T][ks][lane]x8   = 2 MB (B-frags of g)
//   hPack : [b][T][j][lane]x8    = 2 MB (A-frags of h)
//   v1N   : [b][o][l] f32        = 4 MB
// ---------------------------------------------------------------------------

// Kernel 0: pack weights into MFMA fragment order, fp32 -> f16.
__global__ __launch_bounds__(256) void wpack_kernel(
    const float* __restrict__ Wq, const float* __restrict__ Wk,
    const float* __restrict__ Wv, const float* __restrict__ Wv1,
    _Float16* __restrict__ Wpack) {
  const int tid = blockIdx.x * 256 + threadIdx.x;  // 24*256 = 6144
  const int w = tid / 1536;
  const int rem = tid % 1536;
  const int og = rem / 768;
  const int ks = (rem % 768) / 64;
  const int lane = rem % 64;
  const float* src = (w == 0) ? Wq : (w == 1) ? Wk : (w == 2) ? Wv : Wv1;
  const float s = (w == 0) ? LOG2E : 1.0f;
  const int row = og * 32 + (lane & 31);
  const int col = ks * 16 + (lane >> 5) * 8;
  const float* p = src + row * C_ + col;
  const float4 a = *(const float4*)(p);
  const float4 c = *(const float4*)(p + 4);
  half8 o;
  half2v t;
  t = pkrtz(a.x * s, a.y * s); o[0] = t[0]; o[1] = t[1];
  t = pkrtz(a.z * s, a.w * s); o[2] = t[0]; o[3] = t[1];
  t = pkrtz(c.x * s, c.y * s); o[4] = t[0]; o[5] = t[1];
  t = pkrtz(c.z * s, c.w * s); o[6] = t[0]; o[7] = t[1];
  *(half8*)(Wpack + (size_t)tid * 8) = o;
}

// ---------------------------------------------------------------------------
// Kernel 1: projections via MFMA (unchanged from R10, which passed).
// ---------------------------------------------------------------------------
__global__ __launch_bounds__(256) void proj_mfma(
    const float* __restrict__ x, const _Float16* __restrict__ Wpack,
    _Float16* __restrict__ fPack, _Float16* __restrict__ gPack,
    _Float16* __restrict__ hPack, float* __restrict__ v1N) {
  __shared__ __align__(16) _Float16 xT[32][200];   // [l][c], stride 200 halfs
  __shared__ __align__(16) _Float16 fl[32 * 72];
  __shared__ __align__(16) _Float16 gl[32 * 72];
  __shared__ __align__(16) _Float16 hl[64 * 40];
  __shared__ float vl[64][33];
  const int b = blockIdx.y, T = blockIdx.x, l0 = T * 32;
  const int t = threadIdx.x;
  const int lane = t & 63, w = t >> 6;
  const int m = lane & 31, hi = lane >> 5;
  const int lr = lane & 31, rp = lane >> 5;

  // W frags (lane-contiguous; independent of LDS)
  const _Float16* Wp = Wpack + (size_t)w * 1536 * 8;
  half8 wf[2][12];
#pragma unroll
  for (int og = 0; og < 2; ++og)
#pragma unroll
    for (int ks = 0; ks < 12; ++ks)
      wf[og][ks] =
          *(const half8*)(Wp + ((size_t)(og * 12 + ks) * 64 + lane) * 8);

  {  // stage x: wave w converts c-rows [48w, 48w+48) into xT[l][c] f16
    const float* xb = x + (size_t)b * C_ * L_ + l0 + lr;
    const int c0 = w * 48;
#pragma unroll
    for (int i = 0; i < 24; ++i) {
      const int c = c0 + 2 * i + rp;
      xT[lr][c] = (_Float16)xb[(size_t)c * L_];
    }
  }
  __syncthreads();

  // A-frags: x^T rows l (b128 reads), shared by all waves
  half8 aF[12];
#pragma unroll
  for (int ks = 0; ks < 12; ++ks)
    aF[ks] = *(const half8*)&xT[m][ks * 16 + hi * 8];

  f32x16 acc0 = {}, acc1 = {};
#pragma unroll
  for (int ks = 0; ks < 12; ++ks) {
    acc0 = __builtin_amdgcn_mfma_f32_32x32x16_f16(aF[ks], wf[0][ks], acc0, 0, 0, 0);
    acc1 = __builtin_amdgcn_mfma_f32_32x32x16_f16(aF[ks], wf[1][ks], acc1, 0, 0, 0);
  }
  // C-layout: lane m holds o-columns m (acc0) and m+32 (acc1),
  // rows l = 4*hi + 8*(r>>2) + (r&3).

  if (w < 2) {
    _Float16* buf = (w == 0) ? fl : gl;
#pragma unroll
    for (int r = 0; r < 16; ++r) {
      const int l = 4 * hi + 8 * (r >> 2) + (r & 3);
      buf[l * 72 + m] = (_Float16)acc0[r];
      buf[l * 72 + 32 + m] = (_Float16)acc1[r];
    }
    _Float16* dst = ((w == 0) ? fPack : gPack) +
                    (size_t)b * L_ * CO_ + (size_t)T * 4 * 64 * 8;
#pragma unroll
    for (int ks = 0; ks < 4; ++ks) {
      const half8 v =
          *(const half8*)&buf[(lane & 31) * 72 + ks * 16 + (lane >> 5) * 8];
      *(half8*)(dst + ((size_t)ks * 64 + lane) * 8) = v;
    }
  } else if (w == 2) {
#pragma unroll
    for (int r = 0; r < 16; ++r) {
      const int l = 4 * hi + 8 * (r >> 2) + (r & 3);
      hl[m * 40 + l] = (_Float16)acc0[r];
      hl[(32 + m) * 40 + l] = (_Float16)acc1[r];
    }
    _Float16* dst = hPack + (size_t)b * L_ * CO_ + (size_t)T * 4 * 64 * 8;
#pragma unroll
    for (int j = 0; j < 4; ++j) {  // j = oh*2 + ks
      const int oh2 = j >> 1, ks2 = j & 1;
      const half8 v = *(const half8*)&hl[(32 * oh2 + (lane & 31)) * 40 +
                                         ks2 * 16 + (lane >> 5) * 8];
      *(half8*)(dst + ((size_t)j * 64 + lane) * 8) = v;
    }
  } else {
#pragma unroll
    for (int r = 0; r < 16; ++r) {
      const int l = 4 * hi + 8 * (r >> 2) + (r & 3);
      vl[m][l] = acc0[r];
      vl[32 + m][l] = acc1[r];
    }
#pragma unroll
    for (int i = 0; i < 32; ++i) {
      const int o = 2 * i + rp;
      v1N[((size_t)b * CO_ + o) * L_ + l0 + lr] = vl[o][lr];
    }
  }
}

// ---------------------------------------------------------------------------
// Kernel 2: flash attention.  R8 loop structure (S-ahead dropped: proven
// neutral) + Z ACCUMULATED ON THE MATRIX PIPE: Z_m = sum_l P[l][m] via
// mfma(ones, P) into dedicated accs — removes 64 VALU adds + 2 shfls per
// step from the VALU stream (the bottleneck pipe).
// 256 blocks (1/CU; XCD pair -> batch), 512 thr = 8 waves.
// ---------------------------------------------------------------------------
__global__ __launch_bounds__(512, 2) void attn_mfma(
    const _Float16* __restrict__ fPack, const _Float16* __restrict__ gPack,
    const _Float16* __restrict__ hPack, const float* __restrict__ v1N,
    const float* __restrict__ gamma_p, float* __restrict__ out) {
  __shared__ __align__(16) _Float16 Pl[8][64 * 40];
  __shared__ float obuf4[4][CO_][65];
  __shared__ float redM[8][64];
  __shared__ float redZ[8][64];

  const int id = blockIdx.x;                   // 256 blocks
  const int b = (id >> 1) & 3;                 // XCD pair -> batch
  const int mt = ((id & 1) << 5) | (id >> 3);  // 0..63
  const int m0 = mt * 64;
  const int t = threadIdx.x;
  const int lane = t & 63, s = t >> 6;
  const int m = lane & 31, hi = lane >> 5;

  const _Float16* fT = fPack + (size_t)b * L_ * CO_;
  const _Float16* hT = hPack + (size_t)b * L_ * CO_;
  _Float16* Pw = &Pl[s][0];

  // loop-invariant g B-frags for both m-halves
  half8 gf0[4], gf1[4];
  {
    const _Float16* gp = gPack + (size_t)b * L_ * CO_ +
                         (size_t)(2 * mt) * 4 * 64 * 8 + lane * 8;
#pragma unroll
    for (int ks = 0; ks < 4; ++ks) {
      gf0[ks] = *(const half8*)(gp + (size_t)ks * 64 * 8);
      gf1[ks] = *(const half8*)(gp + (size_t)(4 + ks) * 64 * 8);
    }
  }

  half8 ones8;
#pragma unroll
  for (int e = 0; e < 8; ++e) ones8[e] = (_Float16)1.0f;

  f32x16 o0 = {}, o1 = {}, o2 = {}, o3 = {};
  f32x16 oz0 = {}, oz1 = {};  // Z accumulators: every reg = Z for col m
  float mx0 = -1e30f, mx1 = -1e30f;

  const int T0 = s * 16;
  half8 fc[2][4], hc[2][4];
  {  // initial frags, step 0
    const _Float16* fp = fT + ((size_t)T0 * 4 * 64 + lane) * 8;
    const _Float16* hp = hT + ((size_t)T0 * 4 * 64 + lane) * 8;
#pragma unroll
    for (int ks = 0; ks < 4; ++ks) {
      fc[0][ks] = *(const half8*)(fp + (size_t)ks * 64 * 8);
      hc[0][ks] = *(const half8*)(hp + (size_t)ks * 64 * 8);
    }
  }

#pragma unroll 2
  for (int stp = 0; stp < 16; ++stp) {
    const int cur = stp & 1, nxt = cur ^ 1;
    {  // prefetch step+1 (tail reads run into the next ws buffer: harmless)
      const int Tn = T0 + stp + 1;
      const _Float16* fp = fT + ((size_t)Tn * 4 * 64 + lane) * 8;
      const _Float16* hp = hT + ((size_t)Tn * 4 * 64 + lane) * 8;
#pragma unroll
      for (int ks = 0; ks < 4; ++ks) {
        fc[nxt][ks] = *(const half8*)(fp + (size_t)ks * 64 * 8);
        hc[nxt][ks] = *(const half8*)(hp + (size_t)ks * 64 * 8);
      }
    }
    // S for both m-halves (scores in log2 units via Wq pre-scale)
    f32x16 S0 = {}, S1 = {};
#pragma unroll
    for (int ks = 0; ks < 4; ++ks) {
      S0 = __builtin_amdgcn_mfma_f32_32x32x16_f16(fc[cur][ks], gf0[ks], S0, 0, 0, 0);
      S1 = __builtin_amdgcn_mfma_f32_32x32x16_f16(fc[cur][ks], gf1[ks], S1, 0, 0, 0);
    }
    // ---- fused dual online softmax (Z on the matrix pipe) ----
    float t0 = S0[0], t1 = S1[0];
#pragma unroll
    for (int r = 1; r < 16; ++r) {
      t0 = fmaxf(t0, S0[r]);
      t1 = fmaxf(t1, S1[r]);
    }
    t0 = fmaxf(t0, __shfl_xor(t0, 32, 64));
    t1 = fmaxf(t1, __shfl_xor(t1, 32, 64));
    if (__any(t0 > mx0 || t1 > mx1)) {
      const float mn0 = fmaxf(mx0, t0), mn1 = fmaxf(mx1, t1);
      const float c0 = EXP2(mx0 - mn0), c1 = EXP2(mx1 - mn1);
      mx0 = mn0; mx1 = mn1;
#pragma unroll
      for (int r = 0; r < 16; ++r) {
        o0[r] *= c0; o1[r] *= c0; oz0[r] *= c0;
        o2[r] *= c1; o3[r] *= c1; oz1[r] *= c1;
      }
    }
#pragma unroll
    for (int u = 0; u < 4; ++u) {
      const float a0 = EXP2(S0[4 * u + 0] - mx0);
      const float a1 = EXP2(S0[4 * u + 1] - mx0);
      const float a2 = EXP2(S0[4 * u + 2] - mx0);
      const float a3 = EXP2(S0[4 * u + 3] - mx0);
      const half2v lo = pkrtz(a0, a1);
      const half2v hi2 = pkrtz(a2, a3);
      half4v w4; w4[0] = lo[0]; w4[1] = lo[1]; w4[2] = hi2[0]; w4[3] = hi2[1];
      *(half4v*)(Pw + m * 40 + 4 * hi + 8 * u) = w4;
      const float b0 = EXP2(S1[4 * u + 0] - mx1);
      const float b1 = EXP2(S1[4 * u + 1] - mx1);
      const float b2 = EXP2(S1[4 * u + 2] - mx1);
      const float b3 = EXP2(S1[4 * u + 3] - mx1);
      const half2v lo2 = pkrtz(b0, b1);
      const half2v hi3 = pkrtz(b2, b3);
      half4v w5; w5[0] = lo2[0]; w5[1] = lo2[1]; w5[2] = hi3[0]; w5[3] = hi3[1];
      *(half4v*)(Pw + (32 + m) * 40 + 4 * hi + 8 * u) = w5;
    }
    // single LDS wait leg: all 4 P-frag reads together
    const half8 bP0 = *(const half8*)(Pw + m * 40 + 8 * hi);
    const half8 bP1 = *(const half8*)(Pw + m * 40 + 16 + 8 * hi);
    const half8 bQ0 = *(const half8*)(Pw + (32 + m) * 40 + 8 * hi);
    const half8 bQ1 = *(const half8*)(Pw + (32 + m) * 40 + 16 + 8 * hi);
    o0 = __builtin_amdgcn_mfma_f32_32x32x16_f16(hc[cur][0], bP0, o0, 0, 0, 0);
    o1 = __builtin_amdgcn_mfma_f32_32x32x16_f16(hc[cur][2], bP0, o1, 0, 0, 0);
    o2 = __builtin_amdgcn_mfma_f32_32x32x16_f16(hc[cur][0], bQ0, o2, 0, 0, 0);
    o3 = __builtin_amdgcn_mfma_f32_32x32x16_f16(hc[cur][2], bQ0, o3, 0, 0, 0);
    oz0 = __builtin_amdgcn_mfma_f32_32x32x16_f16(ones8, bP0, oz0, 0, 0, 0);
    oz1 = __builtin_amdgcn_mfma_f32_32x32x16_f16(ones8, bQ0, oz1, 0, 0, 0);
    o0 = __builtin_amdgcn_mfma_f32_32x32x16_f16(hc[cur][1], bP1, o0, 0, 0, 0);
    o1 = __builtin_amdgcn_mfma_f32_32x32x16_f16(hc[cur][3], bP1, o1, 0, 0, 0);
    o2 = __builtin_amdgcn_mfma_f32_32x32x16_f16(hc[cur][1], bQ1, o2, 0, 0, 0);
    o3 = __builtin_amdgcn_mfma_f32_32x32x16_f16(hc[cur][3], bQ1, o3, 0, 0, 0);
    oz0 = __builtin_amdgcn_mfma_f32_32x32x16_f16(ones8, bP1, oz0, 0, 0, 0);
    oz1 = __builtin_amdgcn_mfma_f32_32x32x16_f16(ones8, bQ1, oz1, 0, 0, 0);
  }

  // ---- merge the 8 l-partitions ----
  // oz0[0] = Z for column m (every reg/lane-half holds the same value).
  const float Z0 = oz0[0];
  const float Z1 = oz1[0];
  if (hi == 0) {
    redM[s][m] = mx0; redM[s][m + 32] = mx1;
    redZ[s][m] = Z0;  redZ[s][m + 32] = Z1;
  }
  __syncthreads();
  float M0 = redM[0][m], M1 = redM[0][m + 32];
#pragma unroll
  for (int i = 1; i < 8; ++i) {
    M0 = fmaxf(M0, redM[i][m]);
    M1 = fmaxf(M1, redM[i][m + 32]);
  }
  const float sc0 = EXP2(mx0 - M0);
  const float sc1 = EXP2(mx1 - M1);
  if (s < 4) {
#pragma unroll
    for (int r = 0; r < 16; ++r) {
      const int o = 4 * hi + 8 * (r >> 2) + (r & 3);
      obuf4[s][o][m] = sc0 * o0[r];
      obuf4[s][o + 32][m] = sc0 * o1[r];
      obuf4[s][o][m + 32] = sc1 * o2[r];
      obuf4[s][o + 32][m + 32] = sc1 * o3[r];
    }
  }
  __syncthreads();
  if (s >= 4) {
#pragma unroll
    for (int r = 0; r < 16; ++r) {
      const int o = 4 * hi + 8 * (r >> 2) + (r & 3);
      obuf4[s - 4][o][m] += sc0 * o0[r];
      obuf4[s - 4][o + 32][m] += sc0 * o1[r];
      obuf4[s - 4][o][m + 32] += sc1 * o2[r];
      obuf4[s - 4][o + 32][m + 32] += sc1 * o3[r];
    }
  }
  __syncthreads();

  // epilogue: out = gamma * O / Zt + v1
  const float gam = gamma_p[0];
  const int me = t & 63;   // m column
  const int og = t >> 6;   // 0..7
  float M = redM[0][me];
#pragma unroll
  for (int i = 1; i < 8; ++i) M = fmaxf(M, redM[i][me]);
  float Zt = 0.f;
#pragma unroll
  for (int i = 0; i < 8; ++i) Zt += EXP2(redM[i][me] - M) * redZ[i][me];
  const float inv = 1.0f / Zt;
#pragma unroll
  for (int i = 0; i < 8; ++i) {
    const int o = og * 8 + i;
    const float val = obuf4[0][o][me] + obuf4[1][o][me] +
                      obuf4[2][o][me] + obuf4[3][o][me];
    const size_t g = ((size_t)b * CO_ + o) * L_ + m0 + me;
    out[g] = gam * val * inv + v1N[g];
  }
}

extern "C" void kernel_launch(void* const* d_in, const int* in_sizes, int n_in,
                              void* d_out, int out_size, void* d_ws,
                              size_t ws_size, hipStream_t stream) {
  const float* x = (const float*)d_in[0];
  const float* Wq = (const float*)d_in[1];
  const float* Wk = (const float*)d_in[2];
  const float* Wv = (const float*)d_in[3];
  const float* Wv1 = (const float*)d_in[4];
  const float* gamma = (const float*)d_in[5];
  float* out = (float*)d_out;

  _Float16* Wpack = (_Float16*)d_ws;                 // 49152 halfs (96 KB)
  _Float16* fPack = Wpack + (size_t)4 * 1536 * 8;
  _Float16* gPack = fPack + (size_t)B_ * L_ * CO_;
  _Float16* hPack = gPack + (size_t)B_ * L_ * CO_;
  float* v1N = (float*)(hPack + (size_t)B_ * L_ * CO_);

  wpack_kernel<<<24, 256, 0, stream>>>(Wq, Wk, Wv, Wv1, Wpack);
  proj_mfma<<<dim3(L_ / 32, B_), 256, 0, stream>>>(x, Wpack, fPack, gPack,
                                                   hPack, v1N);
  attn_mfma<<<256, 512, 0, stream>>>(fPack, gPack, hPack, v1N, gamma, out);
}